// Round 2
// baseline (831.076 us; speedup 1.0000x reference)
//
#include <hip/hip_runtime.h>

#define BTOT   131072
#define INDIM  128
#define OUTDIM 512
#define VBS    128
#define NCHUNK (BTOT / VBS)   // 1024
#define MAXIT  16             // Michelot max iterations (early exit, typ. 3-5)
#define TTOL   1e-4f          // tau convergence tolerance
#define EPS    1e-5f

typedef _Float16 half8  __attribute__((ext_vector_type(8)));
typedef _Float16 half2t __attribute__((ext_vector_type(2)));
typedef float    floatx4 __attribute__((ext_vector_type(4)));

// ---------------------------------------------------------------------------
// Kernel 1: convert W [512x128] fp32 -> fp16 into workspace (row-major [o][k])
// ---------------------------------------------------------------------------
__global__ void w_to_half_kernel(const float* __restrict__ W,
                                 _Float16* __restrict__ Wh) {
    int i = blockIdx.x * blockDim.x + threadIdx.x;   // float4 index, 0..16383
    const float4 v = ((const float4*)W)[i];
    union { _Float16 h[4]; uint2 u; } p;
    p.h[0] = (_Float16)v.x; p.h[1] = (_Float16)v.y;
    p.h[2] = (_Float16)v.z; p.h[3] = (_Float16)v.w;
    ((uint2*)Wh)[i] = p.u;
}

// ---------------------------------------------------------------------------
// Kernel 2: fused GEMM(fp16 MFMA) + GhostBN + priors + sparsemax.
// One block = one virtual batch (128 rows x 512 cols), 8 waves, wave owns
// 16 rows x 512 cols as 32 MFMA col-tiles. Tile state is packed to fp16
// (64 VGPRs) so combined reg use stays <=128 -> 4 waves/SIMD.
// acc layout per tile t: col = t*16 + (lane&15), row = (lane>>4)*4 + reg.
// ---------------------------------------------------------------------------
__launch_bounds__(512, 4)
__global__ void fused_kernel(const float* __restrict__ priors,
                             const float* __restrict__ feat,
                             const _Float16* __restrict__ Wh,
                             const float* __restrict__ gamma,
                             const float* __restrict__ beta,
                             float* __restrict__ out)
{
    __shared__ float lds_sum[8][OUTDIM];
    __shared__ float lds_sq [8][OUTDIM];
    __shared__ float lds_a[OUTDIM];
    __shared__ float lds_b[OUTDIM];

    const int tid  = threadIdx.x;
    const int w    = tid >> 6;      // wave 0..7
    const int lane = tid & 63;
    const int i16  = lane & 15;
    const int quad = lane >> 4;     // 0..3
    const int row0 = blockIdx.x * VBS + w * 16;   // wave's first global row

    // ---- load A fragments (fp32 global -> fp16 regs) ----
    // A operand layout: A[m = lane&15][k = quad*8 + j], j=0..7, per 32-wide k-tile
    half8 afrag[4];
    {
        const float* ap = feat + (size_t)(row0 + i16) * INDIM + quad * 8;
        #pragma unroll
        for (int kt = 0; kt < 4; ++kt) {
            float4 v0 = *(const float4*)(ap + kt * 32);
            float4 v1 = *(const float4*)(ap + kt * 32 + 4);
            half8 h;
            h[0]=(_Float16)v0.x; h[1]=(_Float16)v0.y; h[2]=(_Float16)v0.z; h[3]=(_Float16)v0.w;
            h[4]=(_Float16)v1.x; h[5]=(_Float16)v1.y; h[6]=(_Float16)v1.z; h[7]=(_Float16)v1.w;
            afrag[kt] = h;
        }
    }

    // ---- Phase 1: GEMM + per-column stats (fp32), pack tile to fp16 regs ----
    half2t yh[64];   // yh[2t] = rows(+0,+1), yh[2t+1] = rows(+2,+3) of col-tile t
    {
        const half8* wp0 = (const half8*)(Wh + (size_t)i16 * INDIM + quad * 8);
        #pragma unroll
        for (int t = 0; t < 32; ++t) {
            floatx4 c = {0.f, 0.f, 0.f, 0.f};
            #pragma unroll
            for (int kt = 0; kt < 4; ++kt) {
                half8 b = wp0[t * 256 + kt * 4];
                c = __builtin_amdgcn_mfma_f32_16x16x32_f16(afrag[kt], b, c, 0, 0, 0);
            }
            float s = c.x + c.y + c.z + c.w;
            float q = c.x*c.x + c.y*c.y + c.z*c.z + c.w*c.w;
            s += __shfl_xor(s, 16); q += __shfl_xor(q, 16);
            s += __shfl_xor(s, 32); q += __shfl_xor(q, 32);
            if (quad == 0) {
                lds_sum[w][t * 16 + i16] = s;
                lds_sq [w][t * 16 + i16] = q;
            }
            half2t h01 = {(_Float16)c.x, (_Float16)c.y};
            half2t h23 = {(_Float16)c.z, (_Float16)c.w};
            yh[2 * t]     = h01;
            yh[2 * t + 1] = h23;
        }
    }
    __syncthreads();
    {
        // 512 threads: one column each -> BN affine coefficients
        float s = 0.f, q = 0.f;
        #pragma unroll
        for (int j = 0; j < 8; ++j) { s += lds_sum[j][tid]; q += lds_sq[j][tid]; }
        float mean = s * (1.0f / VBS);
        float var  = q * (1.0f / VBS) - mean * mean;
        float rstd = 1.0f / sqrtf(var + EPS);
        float a = gamma[tid] * rstd;
        float b = beta[tid] - mean * a;
        lds_a[tid] = a;
        lds_b[tid] = b;
    }
    __syncthreads();

    // ---- Phase 2: normalize + priors, repack fp16, track row max (rounded) ----
    const float* pbase = priors + (size_t)(row0 + quad * 4) * OUTDIM + i16;
    float mx0 = -3.4e38f, mx1 = -3.4e38f, mx2 = -3.4e38f, mx3 = -3.4e38f;
    #pragma unroll
    for (int t = 0; t < 32; ++t) {
        const int col = t * 16 + i16;
        const float a = lds_a[col];
        const float b = lds_b[col];
        float p0 = pbase[t * 16];
        float p1 = pbase[OUTDIM + t * 16];
        float p2 = pbase[2 * OUTDIM + t * 16];
        float p3 = pbase[3 * OUTDIM + t * 16];
        half2t h01 = yh[2 * t], h23 = yh[2 * t + 1];
        float y0 = fmaf((float)h01[0], a, b) * p0;
        float y1 = fmaf((float)h01[1], a, b) * p1;
        float y2 = fmaf((float)h23[0], a, b) * p2;
        float y3 = fmaf((float)h23[1], a, b) * p3;
        half2t n01 = {(_Float16)y0, (_Float16)y1};
        half2t n23 = {(_Float16)y2, (_Float16)y3};
        yh[2 * t]     = n01;
        yh[2 * t + 1] = n23;
        // max over the ROUNDED values so tau0 = max-1 is a valid superset start
        mx0 = fmaxf(mx0, (float)n01[0]); mx1 = fmaxf(mx1, (float)n01[1]);
        mx2 = fmaxf(mx2, (float)n23[0]); mx3 = fmaxf(mx3, (float)n23[1]);
    }
    #pragma unroll
    for (int d = 1; d < 16; d <<= 1) {
        mx0 = fmaxf(mx0, __shfl_xor(mx0, d));
        mx1 = fmaxf(mx1, __shfl_xor(mx1, d));
        mx2 = fmaxf(mx2, __shfl_xor(mx2, d));
        mx3 = fmaxf(mx3, __shfl_xor(mx3, d));
    }

    // ---- Phase 3: Michelot fixed point with early exit ----
    // tau' = tau + (sum(relu(x - tau)) - 1) / count(x > tau); tau0 = max - 1.
    float t0 = mx0 - 1.0f, t1 = mx1 - 1.0f, t2 = mx2 - 1.0f, t3 = mx3 - 1.0f;
    #pragma unroll 1
    for (int it = 0; it < MAXIT; ++it) {
        float s0 = 0.f, s1 = 0.f, s2 = 0.f, s3 = 0.f;
        float k0 = 0.f, k1 = 0.f, k2 = 0.f, k3 = 0.f;
        #pragma unroll
        for (int t = 0; t < 32; ++t) {
            half2t h01 = yh[2 * t], h23 = yh[2 * t + 1];
            float d0 = (float)h01[0] - t0;
            float d1 = (float)h01[1] - t1;
            float d2 = (float)h23[0] - t2;
            float d3 = (float)h23[1] - t3;
            s0 += fmaxf(d0, 0.f); k0 += (d0 > 0.f) ? 1.f : 0.f;
            s1 += fmaxf(d1, 0.f); k1 += (d1 > 0.f) ? 1.f : 0.f;
            s2 += fmaxf(d2, 0.f); k2 += (d2 > 0.f) ? 1.f : 0.f;
            s3 += fmaxf(d3, 0.f); k3 += (d3 > 0.f) ? 1.f : 0.f;
        }
        #pragma unroll
        for (int d = 1; d < 16; d <<= 1) {
            s0 += __shfl_xor(s0, d); k0 += __shfl_xor(k0, d);
            s1 += __shfl_xor(s1, d); k1 += __shfl_xor(k1, d);
            s2 += __shfl_xor(s2, d); k2 += __shfl_xor(k2, d);
            s3 += __shfl_xor(s3, d); k3 += __shfl_xor(k3, d);
        }
        float n0 = t0 + (s0 - 1.0f) * __builtin_amdgcn_rcpf(k0);
        float n1 = t1 + (s1 - 1.0f) * __builtin_amdgcn_rcpf(k1);
        float n2 = t2 + (s2 - 1.0f) * __builtin_amdgcn_rcpf(k2);
        float n3 = t3 + (s3 - 1.0f) * __builtin_amdgcn_rcpf(k3);
        bool changed = (fabsf(n0 - t0) > TTOL) | (fabsf(n1 - t1) > TTOL) |
                       (fabsf(n2 - t2) > TTOL) | (fabsf(n3 - t3) > TTOL);
        t0 = n0; t1 = n1; t2 = n2; t3 = n3;
        if (!__any(changed)) break;
    }

    // ---- Phase 4: write output: relu(x - tau) ----
    float* obase = out + (size_t)(row0 + quad * 4) * OUTDIM + i16;
    #pragma unroll
    for (int t = 0; t < 32; ++t) {
        half2t h01 = yh[2 * t], h23 = yh[2 * t + 1];
        obase[t * 16]              = fmaxf((float)h01[0] - t0, 0.f);
        obase[OUTDIM + t * 16]     = fmaxf((float)h01[1] - t1, 0.f);
        obase[2 * OUTDIM + t * 16] = fmaxf((float)h23[0] - t2, 0.f);
        obase[3 * OUTDIM + t * 16] = fmaxf((float)h23[1] - t3, 0.f);
    }
}

// ---------------------------------------------------------------------------
extern "C" void kernel_launch(void* const* d_in, const int* in_sizes, int n_in,
                              void* d_out, int out_size, void* d_ws, size_t ws_size,
                              hipStream_t stream) {
    const float* priors = (const float*)d_in[0];
    const float* feat   = (const float*)d_in[1];
    const float* W      = (const float*)d_in[2];
    const float* gamma  = (const float*)d_in[3];
    const float* beta   = (const float*)d_in[4];
    float* out = (float*)d_out;
    _Float16* Wh = (_Float16*)d_ws;   // 512*128*2 = 128 KB

    hipLaunchKernelGGL(w_to_half_kernel, dim3(64), dim3(256), 0, stream, W, Wh);
    hipLaunchKernelGGL(fused_kernel, dim3(NCHUNK), dim3(512), 0, stream,
                       priors, feat, Wh, gamma, beta, out);
}

// Round 3
// 630.840 us; speedup vs baseline: 1.3174x; 1.3174x over previous
//
#include <hip/hip_runtime.h>

#define BTOT   131072
#define INDIM  128
#define OUTDIM 512
#define VBS    128
#define NCHUNK (BTOT / VBS)   // 1024
#define CPB    128            // cols per block (kernel A)
#define MAXIT  16
#define TTOL   1e-4f
#define EPS    1e-5f

typedef _Float16 half8  __attribute__((ext_vector_type(8)));
typedef float    floatx4 __attribute__((ext_vector_type(4)));

// ---------------------------------------------------------------------------
// Kernel 0: convert W [512x128] fp32 -> fp16 into workspace (row-major [o][k])
// ---------------------------------------------------------------------------
__global__ void w_to_half_kernel(const float* __restrict__ W,
                                 _Float16* __restrict__ Wh) {
    int i = blockIdx.x * blockDim.x + threadIdx.x;   // float4 index, 0..16383
    const float4 v = ((const float4*)W)[i];
    union { _Float16 h[4]; uint2 u; } p;
    p.h[0] = (_Float16)v.x; p.h[1] = (_Float16)v.y;
    p.h[2] = (_Float16)v.z; p.h[3] = (_Float16)v.w;
    ((uint2*)Wh)[i] = p.u;
}

// ---------------------------------------------------------------------------
// Kernel A: GEMM(fp16 MFMA) + GhostBN -> LDS tile -> (apply priors) -> fp16
// intermediate, row-major. Block = 128 rows x 128 cols, 512 threads (8 waves),
// wave w owns rows w*16..w*16+15. acc tile t: col=t*16+(lane&15),
// row=(lane>>4)*4+reg.
// ---------------------------------------------------------------------------
__global__ void __launch_bounds__(512)
gemm_bn_kernel(const float* __restrict__ priors,
               const float* __restrict__ feat,
               const _Float16* __restrict__ Wh,
               const float* __restrict__ gamma,
               const float* __restrict__ beta,
               _Float16* __restrict__ inter)
{
    // tile rows padded to 136 halves (272 B) for LDS access patterns
    __shared__ __align__(16) _Float16 lds_tile[128][136];   // 34816 B
    __shared__ float lds_a[CPB];
    __shared__ float lds_b[CPB];
    // stats overlay the tile region (used strictly before the tile is written)
    float* lds_sum = (float*)&lds_tile[0][0];     // [8][128]
    float* lds_sq  = lds_sum + 8 * CPB;           // [8][128]

    const int tid  = threadIdx.x;
    const int w    = tid >> 6;
    const int lane = tid & 63;
    const int i16  = lane & 15;
    const int quad = lane >> 4;
    const int chunk = blockIdx.x >> 2;            // virtual batch 0..1023
    const int cb    = blockIdx.x & 3;             // col block 0..3
    const int col0  = cb * CPB;
    const int row0  = chunk * VBS + w * 16;

    // ---- A fragments: A[m=lane&15][k=quad*8+j] per 32-wide k-tile ----
    half8 afrag[4];
    {
        const float* ap = feat + (size_t)(row0 + i16) * INDIM + quad * 8;
        #pragma unroll
        for (int kt = 0; kt < 4; ++kt) {
            float4 v0 = *(const float4*)(ap + kt * 32);
            float4 v1 = *(const float4*)(ap + kt * 32 + 4);
            half8 h;
            h[0]=(_Float16)v0.x; h[1]=(_Float16)v0.y; h[2]=(_Float16)v0.z; h[3]=(_Float16)v0.w;
            h[4]=(_Float16)v1.x; h[5]=(_Float16)v1.y; h[6]=(_Float16)v1.z; h[7]=(_Float16)v1.w;
            afrag[kt] = h;
        }
    }

    // ---- GEMM: 8 col-tiles of 16x16x32; B[k=quad*8+j][n=lane&15]=W[n][k] ----
    floatx4 acc[8];
    {
        const half8* wp0 = (const half8*)(Wh + (size_t)(col0 + i16) * INDIM + quad * 8);
        #pragma unroll
        for (int t = 0; t < 8; ++t) {
            floatx4 c = {0.f, 0.f, 0.f, 0.f};
            #pragma unroll
            for (int kt = 0; kt < 4; ++kt) {
                half8 b = wp0[t * 256 + kt * 4];
                c = __builtin_amdgcn_mfma_f32_16x16x32_f16(afrag[kt], b, c, 0, 0, 0);
            }
            acc[t] = c;
            // per-column partial stats over this wave's 16 rows (fp32, pre-round)
            float s = c.x + c.y + c.z + c.w;
            float q = c.x*c.x + c.y*c.y + c.z*c.z + c.w*c.w;
            s += __shfl_xor(s, 16); q += __shfl_xor(q, 16);
            s += __shfl_xor(s, 32); q += __shfl_xor(q, 32);
            if (quad == 0) {
                lds_sum[w * CPB + t * 16 + i16] = s;
                lds_sq [w * CPB + t * 16 + i16] = q;
            }
        }
    }
    __syncthreads();
    if (tid < CPB) {
        float s = 0.f, q = 0.f;
        #pragma unroll
        for (int j = 0; j < 8; ++j) { s += lds_sum[j * CPB + tid]; q += lds_sq[j * CPB + tid]; }
        float mean = s * (1.0f / VBS);
        float var  = q * (1.0f / VBS) - mean * mean;
        float rstd = 1.0f / sqrtf(var + EPS);
        float a = gamma[col0 + tid] * rstd;
        float b = beta[col0 + tid] - mean * a;
        lds_a[tid] = a;
        lds_b[tid] = b;
    }
    __syncthreads();

    // ---- normalize (no priors yet), pack fp16 into LDS tile ----
    #pragma unroll
    for (int t = 0; t < 8; ++t) {
        const int c = t * 16 + i16;
        const float a = lds_a[c];
        const float b = lds_b[c];
        floatx4 v = acc[t];
        const int r0 = w * 16 + quad * 4;
        lds_tile[r0 + 0][c] = (_Float16)fmaf(v.x, a, b);
        lds_tile[r0 + 1][c] = (_Float16)fmaf(v.y, a, b);
        lds_tile[r0 + 2][c] = (_Float16)fmaf(v.z, a, b);
        lds_tile[r0 + 3][c] = (_Float16)fmaf(v.w, a, b);
    }
    __syncthreads();

    // ---- stream out: apply priors with coalesced float4 loads, fp16 stores ----
    // 2048 chunks of 8 cols; thread handles 4: j = k*512 + tid -> row=j>>4, cc=j&15
    #pragma unroll
    for (int k = 0; k < 4; ++k) {
        const int j  = k * 512 + tid;
        const int r  = j >> 4;
        const int cc = j & 15;
        const size_t gro = (size_t)(chunk * VBS + r) * OUTDIM + col0 + cc * 8;
        half8 v = *(const half8*)&lds_tile[r][cc * 8];
        float4 p0 = *(const float4*)(priors + gro);
        float4 p1 = *(const float4*)(priors + gro + 4);
        half8 o;
        o[0] = (_Float16)((float)v[0] * p0.x);
        o[1] = (_Float16)((float)v[1] * p0.y);
        o[2] = (_Float16)((float)v[2] * p0.z);
        o[3] = (_Float16)((float)v[3] * p0.w);
        o[4] = (_Float16)((float)v[4] * p1.x);
        o[5] = (_Float16)((float)v[5] * p1.y);
        o[6] = (_Float16)((float)v[6] * p1.z);
        o[7] = (_Float16)((float)v[7] * p1.w);
        *(half8*)(inter + gro) = o;
    }
}

// ---------------------------------------------------------------------------
// Kernel B: sparsemax per row. One wave per 4 rows; row's 512 vals live as
// 8 fp32/lane; Michelot fixed point with wave-wide shuffle reductions.
// ---------------------------------------------------------------------------
__global__ void __launch_bounds__(256)
sparsemax_kernel(const _Float16* __restrict__ inter, float* __restrict__ out)
{
    const int lane = threadIdx.x & 63;
    const int gw   = (blockIdx.x * 256 + threadIdx.x) >> 6;   // 0..32767

    float x[4][8];
    #pragma unroll
    for (int rr = 0; rr < 4; ++rr) {
        const int row = gw * 4 + rr;
        half8 h = *(const half8*)(inter + (size_t)row * OUTDIM + lane * 8);
        #pragma unroll
        for (int j = 0; j < 8; ++j) x[rr][j] = (float)h[j];
    }

    #pragma unroll
    for (int rr = 0; rr < 4; ++rr) {
        const int row = gw * 4 + rr;
        float mx = x[rr][0];
        #pragma unroll
        for (int j = 1; j < 8; ++j) mx = fmaxf(mx, x[rr][j]);
        #pragma unroll
        for (int d = 1; d < 64; d <<= 1) mx = fmaxf(mx, __shfl_xor(mx, d));

        float tau = mx - 1.0f;
        #pragma unroll 1
        for (int it = 0; it < MAXIT; ++it) {
            float s = 0.f, k = 0.f;
            #pragma unroll
            for (int j = 0; j < 8; ++j) {
                float d = x[rr][j] - tau;
                s += fmaxf(d, 0.f);
                k += (d > 0.f) ? 1.f : 0.f;
            }
            #pragma unroll
            for (int d = 1; d < 64; d <<= 1) {
                s += __shfl_xor(s, d);
                k += __shfl_xor(k, d);
            }
            float ntau = tau + (s - 1.0f) / k;
            float delta = fabsf(ntau - tau);
            tau = ntau;
            if (delta <= TTOL) break;
        }

        float4 o0, o1;
        o0.x = fmaxf(x[rr][0] - tau, 0.f); o0.y = fmaxf(x[rr][1] - tau, 0.f);
        o0.z = fmaxf(x[rr][2] - tau, 0.f); o0.w = fmaxf(x[rr][3] - tau, 0.f);
        o1.x = fmaxf(x[rr][4] - tau, 0.f); o1.y = fmaxf(x[rr][5] - tau, 0.f);
        o1.z = fmaxf(x[rr][6] - tau, 0.f); o1.w = fmaxf(x[rr][7] - tau, 0.f);
        float* ob = out + (size_t)row * OUTDIM + lane * 8;
        *(float4*)ob       = o0;
        *(float4*)(ob + 4) = o1;
    }
}

// ---------------------------------------------------------------------------
// Fallback: R1's fused kernel (known-good 385 us) if ws can't hold the
// intermediate. fp32 accumulators live in AGPRs; 2 waves/SIMD.
// ---------------------------------------------------------------------------
__launch_bounds__(512)
__global__ void fused_fallback(const float* __restrict__ priors,
                               const float* __restrict__ feat,
                               const _Float16* __restrict__ Wh,
                               const float* __restrict__ gamma,
                               const float* __restrict__ beta,
                               float* __restrict__ out)
{
    __shared__ float lds_sum[8][OUTDIM];
    __shared__ float lds_sq [8][OUTDIM];
    __shared__ float lds_a[OUTDIM];
    __shared__ float lds_b[OUTDIM];

    const int tid  = threadIdx.x;
    const int w    = tid >> 6;
    const int lane = tid & 63;
    const int i16  = lane & 15;
    const int quad = lane >> 4;
    const int row0 = blockIdx.x * VBS + w * 16;

    half8 afrag[4];
    {
        const float* ap = feat + (size_t)(row0 + i16) * INDIM + quad * 8;
        #pragma unroll
        for (int kt = 0; kt < 4; ++kt) {
            float4 v0 = *(const float4*)(ap + kt * 32);
            float4 v1 = *(const float4*)(ap + kt * 32 + 4);
            half8 h;
            h[0]=(_Float16)v0.x; h[1]=(_Float16)v0.y; h[2]=(_Float16)v0.z; h[3]=(_Float16)v0.w;
            h[4]=(_Float16)v1.x; h[5]=(_Float16)v1.y; h[6]=(_Float16)v1.z; h[7]=(_Float16)v1.w;
            afrag[kt] = h;
        }
    }
    floatx4 acc[32];
    {
        const half8* wp0 = (const half8*)(Wh + (size_t)i16 * INDIM + quad * 8);
        #pragma unroll
        for (int t = 0; t < 32; ++t) {
            floatx4 c = {0.f, 0.f, 0.f, 0.f};
            #pragma unroll
            for (int kt = 0; kt < 4; ++kt) {
                half8 b = wp0[t * 256 + kt * 4];
                c = __builtin_amdgcn_mfma_f32_16x16x32_f16(afrag[kt], b, c, 0, 0, 0);
            }
            acc[t] = c;
        }
    }
    #pragma unroll
    for (int t = 0; t < 32; ++t) {
        floatx4 v = acc[t];
        float s = v.x + v.y + v.z + v.w;
        float q = v.x*v.x + v.y*v.y + v.z*v.z + v.w*v.w;
        s += __shfl_xor(s, 16); q += __shfl_xor(q, 16);
        s += __shfl_xor(s, 32); q += __shfl_xor(q, 32);
        if (quad == 0) { lds_sum[w][t*16+i16] = s; lds_sq[w][t*16+i16] = q; }
    }
    __syncthreads();
    {
        float s = 0.f, q = 0.f;
        #pragma unroll
        for (int j = 0; j < 8; ++j) { s += lds_sum[j][tid]; q += lds_sq[j][tid]; }
        float mean = s * (1.0f / VBS);
        float var  = q * (1.0f / VBS) - mean * mean;
        float rstd = 1.0f / sqrtf(var + EPS);
        float a = gamma[tid] * rstd;
        float b = beta[tid] - mean * a;
        lds_a[tid] = a; lds_b[tid] = b;
    }
    __syncthreads();
    const float* pbase = priors + (size_t)(row0 + quad * 4) * OUTDIM + i16;
    #pragma unroll
    for (int t = 0; t < 32; ++t) {
        const int col = t * 16 + i16;
        const float a = lds_a[col];
        const float b = lds_b[col];
        floatx4 v = acc[t];
        v.x = fmaf(v.x, a, b) * pbase[t*16];
        v.y = fmaf(v.y, a, b) * pbase[OUTDIM + t*16];
        v.z = fmaf(v.z, a, b) * pbase[2*OUTDIM + t*16];
        v.w = fmaf(v.w, a, b) * pbase[3*OUTDIM + t*16];
        acc[t] = v;
    }
    float mx[4] = {-3.4e38f, -3.4e38f, -3.4e38f, -3.4e38f};
    #pragma unroll
    for (int t = 0; t < 32; ++t) {
        floatx4 v = acc[t];
        mx[0] = fmaxf(mx[0], v.x); mx[1] = fmaxf(mx[1], v.y);
        mx[2] = fmaxf(mx[2], v.z); mx[3] = fmaxf(mx[3], v.w);
    }
    #pragma unroll
    for (int r = 0; r < 4; ++r) {
        mx[r] = fmaxf(mx[r], __shfl_xor(mx[r], 1));
        mx[r] = fmaxf(mx[r], __shfl_xor(mx[r], 2));
        mx[r] = fmaxf(mx[r], __shfl_xor(mx[r], 4));
        mx[r] = fmaxf(mx[r], __shfl_xor(mx[r], 8));
    }
    float tau[4] = {mx[0]-1.f, mx[1]-1.f, mx[2]-1.f, mx[3]-1.f};
    for (int it = 0; it < 10; ++it) {
        float s[4] = {0,0,0,0}, c[4] = {0,0,0,0};
        #pragma unroll
        for (int t = 0; t < 32; ++t) {
            floatx4 v = acc[t];
            if (v.x > tau[0]) { s[0] += v.x; c[0] += 1.f; }
            if (v.y > tau[1]) { s[1] += v.y; c[1] += 1.f; }
            if (v.z > tau[2]) { s[2] += v.z; c[2] += 1.f; }
            if (v.w > tau[3]) { s[3] += v.w; c[3] += 1.f; }
        }
        #pragma unroll
        for (int r = 0; r < 4; ++r) {
            s[r] += __shfl_xor(s[r], 1); c[r] += __shfl_xor(c[r], 1);
            s[r] += __shfl_xor(s[r], 2); c[r] += __shfl_xor(c[r], 2);
            s[r] += __shfl_xor(s[r], 4); c[r] += __shfl_xor(c[r], 4);
            s[r] += __shfl_xor(s[r], 8); c[r] += __shfl_xor(c[r], 8);
            tau[r] = (s[r] - 1.0f) * __builtin_amdgcn_rcpf(c[r]);
        }
    }
    float* obase = out + (size_t)(row0 + quad * 4) * OUTDIM + i16;
    #pragma unroll
    for (int t = 0; t < 32; ++t) {
        floatx4 v = acc[t];
        obase[t*16]            = fmaxf(v.x - tau[0], 0.f);
        obase[OUTDIM + t*16]   = fmaxf(v.y - tau[1], 0.f);
        obase[2*OUTDIM + t*16] = fmaxf(v.z - tau[2], 0.f);
        obase[3*OUTDIM + t*16] = fmaxf(v.w - tau[3], 0.f);
    }
}

// ---------------------------------------------------------------------------
extern "C" void kernel_launch(void* const* d_in, const int* in_sizes, int n_in,
                              void* d_out, int out_size, void* d_ws, size_t ws_size,
                              hipStream_t stream) {
    const float* priors = (const float*)d_in[0];
    const float* feat   = (const float*)d_in[1];
    const float* W      = (const float*)d_in[2];
    const float* gamma  = (const float*)d_in[3];
    const float* beta   = (const float*)d_in[4];
    float* out = (float*)d_out;

    _Float16* Wh = (_Float16*)d_ws;                       // 128 KB
    const size_t inter_off = 128 * 1024;
    const size_t need = inter_off + (size_t)BTOT * OUTDIM * sizeof(_Float16);

    hipLaunchKernelGGL(w_to_half_kernel, dim3(64), dim3(256), 0, stream, W, Wh);

    if (ws_size >= need) {
        _Float16* inter = (_Float16*)((char*)d_ws + inter_off);
        hipLaunchKernelGGL(gemm_bn_kernel, dim3(NCHUNK * 4), dim3(512), 0, stream,
                           priors, feat, Wh, gamma, beta, inter);
        hipLaunchKernelGGL(sparsemax_kernel, dim3(BTOT / 16), dim3(256), 0, stream,
                           inter, out);
    } else {
        hipLaunchKernelGGL(fused_fallback, dim3(NCHUNK), dim3(512), 0, stream,
                           priors, feat, Wh, gamma, beta, out);
    }
}

// Round 4
// 617.129 us; speedup vs baseline: 1.3467x; 1.0222x over previous
//
#include <hip/hip_runtime.h>

#define BTOT   131072
#define INDIM  128
#define OUTDIM 512
#define VBS    128
#define NCHUNK (BTOT / VBS)   // 1024
#define MAXIT  16
#define TTOL   1e-4f
#define EPS    1e-5f
#define TSTR   520            // tile row stride in halves (8 halves pad)

typedef _Float16 half8  __attribute__((ext_vector_type(8)));
typedef float    floatx4 __attribute__((ext_vector_type(4)));

// ---------------------------------------------------------------------------
// Kernel 0: convert W [512x128] fp32 -> fp16 into workspace (row-major [o][k])
// ---------------------------------------------------------------------------
__global__ void w_to_half_kernel(const float* __restrict__ W,
                                 _Float16* __restrict__ Wh) {
    int i = blockIdx.x * blockDim.x + threadIdx.x;   // float4 index, 0..16383
    const float4 v = ((const float4*)W)[i];
    union { _Float16 h[4]; uint2 u; } p;
    p.h[0] = (_Float16)v.x; p.h[1] = (_Float16)v.y;
    p.h[2] = (_Float16)v.z; p.h[3] = (_Float16)v.w;
    ((uint2*)Wh)[i] = p.u;
}

// ---------------------------------------------------------------------------
// Fully fused: GEMM(fp16 MFMA) + GhostBN + priors + sparsemax, one block per
// virtual batch of 128 rows. 1024 threads = 16 waves.
//   GEMM: wave (w8 = w&7, ch = w>>3) owns rows w8*16..+15, cols ch*256..+255
//         as 16 MFMA 16x16x32 col-tiles -> 64 fp32 acc regs (fits 128-reg cap).
//   Tile: normalized values staged fp16 in LDS [128][520] (130 KB). BN stat
//         scratch overlays the tile region (dead before tile is written).
//   Sparsemax: wave w owns rows w*8..+7; row read b128 from LDS, priors
//         applied fp32 with coalesced float4 loads, Michelot fixed point
//         (wave-uniform early exit), coalesced fp32 output.
// LDS total: 130 KB tile + 4 KB a/b = 134 KB -> 1 block/CU, 16 waves (50%).
// ---------------------------------------------------------------------------
__global__ void __launch_bounds__(1024)
fused_all(const float* __restrict__ priors,
          const float* __restrict__ feat,
          const _Float16* __restrict__ Wh,
          const float* __restrict__ gamma,
          const float* __restrict__ beta,
          float* __restrict__ out)
{
    __shared__ __align__(16) _Float16 tile[VBS][TSTR];   // 133120 B
    __shared__ float lds_ab[2][OUTDIM];                  // 4096 B
    // stats overlay the tile region: consumed (phase 2) before tile writes
    float* lds_sum = (float*)&tile[0][0];                // [8][512]
    float* lds_sq  = lds_sum + 8 * OUTDIM;               // [8][512]

    const int tid   = threadIdx.x;
    const int w     = tid >> 6;      // wave 0..15
    const int lane  = tid & 63;
    const int i16   = lane & 15;
    const int quad  = lane >> 4;     // 0..3
    const int w8    = w & 7;         // row group 0..7
    const int ch    = w >> 3;        // col half 0..1
    const int chunk = blockIdx.x;
    const int row0  = chunk * VBS + w8 * 16;
    const int cb0   = ch * 256;

    // ---- A fragments: A[m=lane&15][k=quad*8+j] per 32-wide k-tile ----
    half8 afrag[4];
    {
        const float* ap = feat + (size_t)(row0 + i16) * INDIM + quad * 8;
        #pragma unroll
        for (int kt = 0; kt < 4; ++kt) {
            float4 v0 = *(const float4*)(ap + kt * 32);
            float4 v1 = *(const float4*)(ap + kt * 32 + 4);
            half8 h;
            h[0]=(_Float16)v0.x; h[1]=(_Float16)v0.y; h[2]=(_Float16)v0.z; h[3]=(_Float16)v0.w;
            h[4]=(_Float16)v1.x; h[5]=(_Float16)v1.y; h[6]=(_Float16)v1.z; h[7]=(_Float16)v1.w;
            afrag[kt] = h;
        }
    }

    // ---- Phase 1: GEMM (16 col-tiles) + per-column partial stats (fp32) ----
    // B[k=quad*8+j][n=lane&15] = W[cb0 + t*16 + n][k], streamed from L2.
    floatx4 acc[16];
    {
        const half8* wp0 = (const half8*)(Wh + (size_t)(cb0 + i16) * INDIM + quad * 8);
        #pragma unroll
        for (int t = 0; t < 16; ++t) {
            floatx4 c = {0.f, 0.f, 0.f, 0.f};
            #pragma unroll
            for (int kt = 0; kt < 4; ++kt) {
                half8 b = wp0[t * 256 + kt * 4];   // t*16 rows * 128 halves /8; kt*32 halves /8
                c = __builtin_amdgcn_mfma_f32_16x16x32_f16(afrag[kt], b, c, 0, 0, 0);
            }
            acc[t] = c;
            // sum over the wave's 16 rows for column cb0+t*16+i16
            float s = c.x + c.y + c.z + c.w;
            float q = c.x*c.x + c.y*c.y + c.z*c.z + c.w*c.w;
            s += __shfl_xor(s, 16); q += __shfl_xor(q, 16);
            s += __shfl_xor(s, 32); q += __shfl_xor(q, 32);
            if (quad == 0) {
                lds_sum[w8 * OUTDIM + cb0 + t * 16 + i16] = s;
                lds_sq [w8 * OUTDIM + cb0 + t * 16 + i16] = q;
            }
        }
    }
    __syncthreads();

    // ---- Phase 2: reduce stats across the 8 row-groups -> BN affine a,b ----
    if (tid < OUTDIM) {
        float s = 0.f, q = 0.f;
        #pragma unroll
        for (int j = 0; j < 8; ++j) {
            s += lds_sum[j * OUTDIM + tid];
            q += lds_sq [j * OUTDIM + tid];
        }
        float mean = s * (1.0f / VBS);
        float var  = q * (1.0f / VBS) - mean * mean;
        float rstd = 1.0f / sqrtf(var + EPS);
        float a = gamma[tid] * rstd;
        float b = beta[tid] - mean * a;
        lds_ab[0][tid] = a;
        lds_ab[1][tid] = b;
    }
    __syncthreads();

    // ---- Phase 3: normalize acc, pack fp16 into LDS tile (clobbers stats) ----
    {
        const int r0 = w8 * 16 + quad * 4;
        #pragma unroll
        for (int t = 0; t < 16; ++t) {
            const int c = cb0 + t * 16 + i16;
            const float a = lds_ab[0][c];
            const float b = lds_ab[1][c];
            floatx4 v = acc[t];
            tile[r0 + 0][c] = (_Float16)fmaf(v.x, a, b);
            tile[r0 + 1][c] = (_Float16)fmaf(v.y, a, b);
            tile[r0 + 2][c] = (_Float16)fmaf(v.z, a, b);
            tile[r0 + 3][c] = (_Float16)fmaf(v.w, a, b);
        }
    }
    __syncthreads();

    // ---- Phase 4: sparsemax per row; wave w owns rows w*8..w*8+7 ----
    #pragma unroll 2
    for (int rr = 0; rr < 8; ++rr) {
        const int r = w * 8 + rr;
        const size_t grow = (size_t)(chunk * VBS + r) * OUTDIM + lane * 8;

        half8 h = *(const half8*)&tile[r][lane * 8];       // b128, conflict-free
        float4 p0 = *(const float4*)(priors + grow);       // coalesced
        float4 p1 = *(const float4*)(priors + grow + 4);
        float x[8];
        x[0] = (float)h[0] * p0.x; x[1] = (float)h[1] * p0.y;
        x[2] = (float)h[2] * p0.z; x[3] = (float)h[3] * p0.w;
        x[4] = (float)h[4] * p1.x; x[5] = (float)h[5] * p1.y;
        x[6] = (float)h[6] * p1.z; x[7] = (float)h[7] * p1.w;

        float mx = x[0];
        #pragma unroll
        for (int j = 1; j < 8; ++j) mx = fmaxf(mx, x[j]);
        #pragma unroll
        for (int d = 1; d < 64; d <<= 1) mx = fmaxf(mx, __shfl_xor(mx, d));

        // Michelot: tau' = tau + (sum relu(x-tau) - 1)/count(x>tau); tau0=max-1.
        // s,k are wave-uniform after reduction -> uniform break, no divergence.
        float tau = mx - 1.0f;
        #pragma unroll 1
        for (int it = 0; it < MAXIT; ++it) {
            float s = 0.f, k = 0.f;
            #pragma unroll
            for (int j = 0; j < 8; ++j) {
                float d = x[j] - tau;
                s += fmaxf(d, 0.f);
                k += (d > 0.f) ? 1.f : 0.f;
            }
            #pragma unroll
            for (int d = 1; d < 64; d <<= 1) {
                s += __shfl_xor(s, d);
                k += __shfl_xor(k, d);
            }
            float ntau = tau + (s - 1.0f) / k;
            float delta = fabsf(ntau - tau);
            tau = ntau;
            if (delta <= TTOL) break;
        }

        float4 o0, o1;
        o0.x = fmaxf(x[0] - tau, 0.f); o0.y = fmaxf(x[1] - tau, 0.f);
        o0.z = fmaxf(x[2] - tau, 0.f); o0.w = fmaxf(x[3] - tau, 0.f);
        o1.x = fmaxf(x[4] - tau, 0.f); o1.y = fmaxf(x[5] - tau, 0.f);
        o1.z = fmaxf(x[6] - tau, 0.f); o1.w = fmaxf(x[7] - tau, 0.f);
        *(float4*)(out + grow)     = o0;
        *(float4*)(out + grow + 4) = o1;
    }
}

// ---------------------------------------------------------------------------
extern "C" void kernel_launch(void* const* d_in, const int* in_sizes, int n_in,
                              void* d_out, int out_size, void* d_ws, size_t ws_size,
                              hipStream_t stream) {
    const float* priors = (const float*)d_in[0];
    const float* feat   = (const float*)d_in[1];
    const float* W      = (const float*)d_in[2];
    const float* gamma  = (const float*)d_in[3];
    const float* beta   = (const float*)d_in[4];
    float* out = (float*)d_out;
    _Float16* Wh = (_Float16*)d_ws;   // 512*128*2 = 128 KB, only ws use

    hipLaunchKernelGGL(w_to_half_kernel, dim3(64), dim3(256), 0, stream, W, Wh);
    hipLaunchKernelGGL(fused_all, dim3(NCHUNK), dim3(1024), 0, stream,
                       priors, feat, Wh, gamma, beta, out);
}